// Round 4
// baseline (508.138 us; speedup 1.0000x reference)
//
#include <hip/hip_runtime.h>
#include <hip/hip_bf16.h>

#define BB 8
#define CC 256
#define NN 4096
#define LOG2E 1.44269504088896340736f

typedef __attribute__((ext_vector_type(8))) short short8;
typedef __attribute__((ext_vector_type(4))) float f32x4;
typedef __attribute__((ext_vector_type(4))) int i32x4;

static __device__ __forceinline__ unsigned short f2b(float x) {
  __hip_bfloat16 h = __float2bfloat16(x);   // RNE
  return *reinterpret_cast<unsigned short*>(&h);
}
static __device__ __forceinline__ unsigned int pk2(float a, float b) {
  return (unsigned int)f2b(a) | ((unsigned int)f2b(b) << 16);
}

// ---------------------------------------------------------------------------
// ws layout (bytes):
//   m2   @ 0        : [B][N] f32   row max (base-2 units)        131072
//   invD @ 131072   : [B][N] f32   1/denom                       131072
//   wA   @ 262144   : [20 mg][8 kg][64 l][8 e] bf16 W A-frags    163840
//   ball @ 425984   : [320] f32 biases (f rows pre-scaled LOG2E)   1280
//   fA   @ 427520   : [B][256 kg][64 l][8 e] bf16 (f^T*LOG2E)   2097152
//   gB   @ 2524672  : [B][256 ig][64 l][8 e] bf16               2097152
//   hA   @ 4621824  : [B][16 cg][128 kc][64 l][8 e] bf16       16777216
// Frag conventions (mfma_f32_16x16x32_bf16, m89/m91-verified):
//   A[m][k]: lane l holds m=l&15, k=(l>>4)*8+e   (B[k][n] identical bit layout)
//   D[m][n]: lane l reg r holds m=(l>>4)*4+r, n=l&15
// ---------------------------------------------------------------------------

// Kernel 0: W -> A-frags (bf16), LOG2E folded into f rows; biases -> ball.
__global__ __launch_bounds__(256) void k_wprep(
    const float* __restrict__ Wf, const float* __restrict__ bfv,
    const float* __restrict__ Wg, const float* __restrict__ bgv,
    const float* __restrict__ Wh, const float* __restrict__ bhv,
    unsigned short* __restrict__ wA, float* __restrict__ ball)
{
  const int t = threadIdx.x;
  const int fi = blockIdx.x * 4 + (t >> 6);   // frag index 0..159 (mg*8+kg)
  const int l = t & 63;
  const int mg = fi >> 3, kg = fi & 7;
  const int o = mg * 16 + (l & 15);
  const int c0 = kg * 32 + (l >> 4) * 8;
  const float* src; float scale = 1.0f;
  if (o < 32)      { src = Wf + (size_t)o * CC; scale = LOG2E; }
  else if (o < 64) { src = Wg + (size_t)(o - 32) * CC; }
  else             { src = Wh + (size_t)(o - 64) * CC; }
  float4 a = *(const float4*)(src + c0);
  float4 c = *(const float4*)(src + c0 + 4);
  short8 v;
  v[0] = (short)f2b(a.x * scale); v[1] = (short)f2b(a.y * scale);
  v[2] = (short)f2b(a.z * scale); v[3] = (short)f2b(a.w * scale);
  v[4] = (short)f2b(c.x * scale); v[5] = (short)f2b(c.y * scale);
  v[6] = (short)f2b(c.z * scale); v[7] = (short)f2b(c.w * scale);
  *(short8*)(wA + (size_t)fi * 512 + l * 8) = v;
  if (blockIdx.x == 0 && t < 320)
    ball[t] = (t < 32) ? bfv[t] * LOG2E : (t < 64) ? bgv[t - 32] : bhv[t - 64];
}

// Kernel 1: fused projection GEMM (bf16 MFMA) -> frag-ready fA/gB/hA.
__global__ __launch_bounds__(512) void k_fgh(
    const float* __restrict__ x, const unsigned short* __restrict__ wA,
    const float* __restrict__ ball,
    unsigned short* __restrict__ fA, unsigned short* __restrict__ gB,
    unsigned short* __restrict__ hA)
{
  __shared__ __align__(16) char smem[41984];       // max(xb 8KB, TL 41KB)
  unsigned short* xb = (unsigned short*)smem;      // [8 frag][64 l][8 e]
  unsigned short* TL = (unsigned short*)smem;      // [64 i][328 o] bf16
  const int bid = blockIdx.x;
  const int b = bid & 7, i0 = (bid >> 3) * 64;     // batch pinned to XCD
  const int t = threadIdx.x, w = t >> 6, l = t & 63;
  const int ig_w = w & 3, mg0 = (w >> 2) * 10;
  f32x4 acc[10] = {};
  for (int cc = 0; cc < 4; ++cc) {                 // c-chunks of 64
    __syncthreads();
    {  // stage x[cc*64..+64][i0..i0+64] as 8 B-frags (bf16)
      short8 v;
      const float* xp = x + ((size_t)b * CC + cc * 64 + w * 8) * NN + i0 + l;
      #pragma unroll
      for (int e = 0; e < 8; ++e) v[e] = (short)f2b(xp[(size_t)e * NN]);
      int frag = (w >> 2) * 4 + (l >> 4);
      int lp = (w & 3) * 16 + (l & 15);
      *(short8*)(xb + (frag * 64 + lp) * 8) = v;
    }
    __syncthreads();
    #pragma unroll
    for (int kg2 = 0; kg2 < 2; ++kg2) {
      short8 bfrag = *(const short8*)(xb + ((kg2 * 4 + ig_w) * 64 + l) * 8);
      int kg = cc * 2 + kg2;
      #pragma unroll
      for (int j = 0; j < 10; ++j) {
        short8 afrag = *(const short8*)(wA +
            ((size_t)((mg0 + j) * 8 + kg)) * 512 + l * 8);
        acc[j] = __builtin_amdgcn_mfma_f32_16x16x32_bf16(afrag, bfrag, acc[j], 0, 0, 0);
      }
    }
  }
  __syncthreads();
  // D-frags (+bias) -> transpose tile TL[i][o]
  #pragma unroll
  for (int j = 0; j < 10; ++j) {
    int ob = (mg0 + j) * 16 + (l >> 4) * 4;
    float4 bl = *(const float4*)(ball + ob);
    int irow = ig_w * 16 + (l & 15);
    ushort4 pv;
    pv.x = f2b(acc[j][0] + bl.x); pv.y = f2b(acc[j][1] + bl.y);
    pv.z = f2b(acc[j][2] + bl.z); pv.w = f2b(acc[j][3] + bl.w);
    *(ushort4*)(TL + irow * 328 + ob) = pv;
  }
  __syncthreads();
  // pack fA (o 0..31, already LOG2E-scaled) and gB (o 32..63)
  if (t < 256) {
    int kg_p = t >> 6;
    int o8 = (l >> 4) * 8;
    int irow = kg_p * 16 + (l & 15);
    short8 vf = *(const short8*)(TL + irow * 328 + o8);
    short8 vg = *(const short8*)(TL + irow * 328 + 32 + o8);
    size_t kgG = (size_t)b * 256 + (i0 >> 4) + kg_p;
    *(short8*)(fA + kgG * 512 + l * 8) = vf;
    *(short8*)(gB + kgG * 512 + l * 8) = vg;
  }
  // pack hA (o 64..319): 32 frags x 64 lanes over 512 threads
  #pragma unroll
  for (int q = 0; q < 4; ++q) {
    int slot = t + q * 512;
    int fr = slot >> 6, ll = slot & 63;
    int cg = fr >> 1, kcl = fr & 1;
    int orow = 64 + cg * 16 + (ll & 15);
    int pbase = kcl * 32 + (ll >> 4) * 8;
    short8 v;
    #pragma unroll
    for (int e = 0; e < 8; ++e) v[e] = (short)TL[(pbase + e) * 328 + orow];
    size_t idx = (((size_t)b * 16 + cg) * 128 + (i0 >> 5) + kcl) * 512 + ll * 8;
    *(short8*)(hA + idx) = v;
  }
}

// Kernel 2: single-pass online softmax stats. 4 waves x 32 k-rows; B-frags
// of g streamed straight from L1/L2 (no LDS, no barriers).
__global__ __launch_bounds__(256) void k_stats(
    const unsigned short* __restrict__ fA, const unsigned short* __restrict__ gB,
    float* __restrict__ m2, float* __restrict__ invD)
{
  const int bid = blockIdx.x;
  const int b = bid & 7, kt = bid >> 3;            // 32 ktiles of 128 rows
  const int t = threadIdx.x, w = t >> 6, l = t & 63;
  const int li = l & 15, lh = l >> 4;
  const unsigned short* fb = fA + ((size_t)b * 256 + kt * 8 + w * 2) * 512 + l * 8;
  short8 a0 = *(const short8*)fb;
  short8 a1 = *(const short8*)(fb + 512);
  const unsigned short* gb = gB + (size_t)b * 256 * 512 + l * 8;
  f32x4 zero = {0.f, 0.f, 0.f, 0.f};
  float m[2][4], s[2][4];
  #pragma unroll
  for (int f = 0; f < 2; ++f)
    #pragma unroll
    for (int r = 0; r < 4; ++r) { m[f][r] = -1e30f; s[f][r] = 0.f; }
  for (int j4 = 0; j4 < 64; ++j4) {
    f32x4 d[2][4];
    #pragma unroll
    for (int jj = 0; jj < 4; ++jj) {
      short8 bf = *(const short8*)(gb + (size_t)(j4 * 4 + jj) * 512);
      d[0][jj] = __builtin_amdgcn_mfma_f32_16x16x32_bf16(a0, bf, zero, 0, 0, 0);
      d[1][jj] = __builtin_amdgcn_mfma_f32_16x16x32_bf16(a1, bf, zero, 0, 0, 0);
    }
    #pragma unroll
    for (int f = 0; f < 2; ++f)
      #pragma unroll
      for (int r = 0; r < 4; ++r) {
        float cm = fmaxf(fmaxf(d[f][0][r], d[f][1][r]),
                         fmaxf(d[f][2][r], d[f][3][r]));
        float mn = fmaxf(m[f][r], cm);
        float a = (exp2f(d[f][0][r] - mn) + exp2f(d[f][1][r] - mn))
                + (exp2f(d[f][2][r] - mn) + exp2f(d[f][3][r] - mn));
        s[f][r] = s[f][r] * exp2f(m[f][r] - mn) + a;
        m[f][r] = mn;
      }
  }
  // merge over the 16 j-lane columns
  #pragma unroll
  for (int mk = 1; mk < 16; mk <<= 1)
    #pragma unroll
    for (int f = 0; f < 2; ++f)
      #pragma unroll
      for (int r = 0; r < 4; ++r) {
        float om = __shfl_xor(m[f][r], mk);
        float os = __shfl_xor(s[f][r], mk);
        float mn = fmaxf(m[f][r], om);
        s[f][r] = s[f][r] * exp2f(m[f][r] - mn) + os * exp2f(om - mn);
        m[f][r] = mn;
      }
  if (li == 0) {
    #pragma unroll
    for (int f = 0; f < 2; ++f)
      #pragma unroll
      for (int r = 0; r < 4; ++r) {
        size_t idx = (size_t)b * NN + kt * 128 + w * 32 + f * 16 + lh * 4 + r;
        m2[idx] = m[f][r];
        invD[idx] = 1.0f / s[f][r];
      }
  }
}

// Kernel 3: out^T path: out[c][i] via D = P^T . h^T. No LDS, no barriers.
// 4 waves x i-strip 16; each wave covers all 256 c. P exchanged D->A-frag
// in-register via ds_bpermute (lane-group permutation, l&15 invariant).
__global__ __launch_bounds__(256) void k_out(
    const unsigned short* __restrict__ fA, const unsigned short* __restrict__ gB,
    const unsigned short* __restrict__ hA,
    const float* __restrict__ m2v, const float* __restrict__ invDv,
    const float* __restrict__ x, const float* __restrict__ gamma,
    float* __restrict__ out)
{
  const int bid = blockIdx.x;
  const int b = bid & 7, i0 = (bid >> 3) * 64;     // batch pinned to XCD
  const int t = threadIdx.x, w = t >> 6, l = t & 63;
  const int li = l & 15, lh = l >> 4;
  const unsigned short* fAb = fA + (size_t)b * 256 * 512;
  const unsigned short* hAb = hA + (size_t)b * 16 * 128 * 512;
  short8 gfrag = *(const short8*)(gB +
      ((size_t)b * 256 + (i0 >> 4) + w) * 512 + l * 8);
  const float* m2 = m2v + (size_t)b * NN;
  const float* invD = invDv + (size_t)b * NN;
  // bpermute byte addrs: src lane = 32*(q&1) + 16*(j>>1) + li  (q = lh)
  const int adr0 = ((lh & 1) * 32 + li) * 4;        // j = 0,1
  const int adr1 = ((lh & 1) * 32 + 16 + li) * 4;   // j = 2,3
  const bool hiSel = (lh & 2) != 0;                 // target kg-parity = q>>1
  f32x4 zero = {0.f, 0.f, 0.f, 0.f};
  f32x4 acc[16] = {};
  for (int ch = 0; ch < 64; ++ch) {
    // ---- S phase: 4 S-frags (k = ch*64..+64, i = i0+w*16..+16) -> packed P
    unsigned int pw[4][2];
    #pragma unroll
    for (int kg2 = 0; kg2 < 4; ++kg2) {
      short8 af = *(const short8*)(fAb + (size_t)(ch * 4 + kg2) * 512 + l * 8);
      f32x4 sfr = __builtin_amdgcn_mfma_f32_16x16x32_bf16(af, gfrag, zero, 0, 0, 0);
      const int kb = ch * 64 + kg2 * 16 + lh * 4;
      float4 mm = *(const float4*)(m2 + kb);
      float4 dd = *(const float4*)(invD + kb);
      pw[kg2][0] = pk2(exp2f(sfr[0] - mm.x) * dd.x, exp2f(sfr[1] - mm.y) * dd.y);
      pw[kg2][1] = pk2(exp2f(sfr[2] - mm.z) * dd.z, exp2f(sfr[3] - mm.w) * dd.w);
    }
    // ---- exchange: D layout -> 2 PV A-frags (P^T), pure lane-group moves
    i32x4 paw[2];
    #pragma unroll
    for (int s2 = 0; s2 < 2; ++s2) {
      #pragma unroll
      for (int j = 0; j < 4; ++j) {
        const int adr = (j >= 2) ? adr1 : adr0;
        int ua = __builtin_amdgcn_ds_bpermute(adr, (int)pw[2 * s2][j & 1]);
        int ub = __builtin_amdgcn_ds_bpermute(adr, (int)pw[2 * s2 + 1][j & 1]);
        paw[s2][j] = hiSel ? ub : ua;
      }
    }
    short8 pA0 = __builtin_bit_cast(short8, paw[0]);
    short8 pA1 = __builtin_bit_cast(short8, paw[1]);
    // ---- PV phase: 32 MFMA, h B-frags from L1/L2 (shared across waves)
    #pragma unroll
    for (int cg = 0; cg < 16; ++cg) {
      const unsigned short* hb = hAb + ((size_t)cg * 128 + ch * 2) * 512 + l * 8;
      short8 h0 = *(const short8*)hb;
      short8 h1 = *(const short8*)(hb + 512);
      acc[cg] = __builtin_amdgcn_mfma_f32_16x16x32_bf16(pA0, h0, acc[cg], 0, 0, 0);
      acc[cg] = __builtin_amdgcn_mfma_f32_16x16x32_bf16(pA1, h1, acc[cg], 0, 0, 0);
    }
  }
  // epilogue: D[m=i][n=c] -> 4 consecutive i per lane = float4 store
  const float gm = gamma[0];
  const int ib = i0 + w * 16 + lh * 4;
  #pragma unroll
  for (int cg = 0; cg < 16; ++cg) {
    int c = cg * 16 + li;
    size_t off = ((size_t)b * CC + c) * NN + ib;
    float4 xv = *(const float4*)(x + off);
    float4 ov;
    ov.x = gm * acc[cg][0] + xv.x;
    ov.y = gm * acc[cg][1] + xv.y;
    ov.z = gm * acc[cg][2] + xv.z;
    ov.w = gm * acc[cg][3] + xv.w;
    *(float4*)(out + off) = ov;
  }
}

extern "C" void kernel_launch(void* const* d_in, const int* in_sizes, int n_in,
                              void* d_out, int out_size, void* d_ws, size_t ws_size,
                              hipStream_t stream)
{
  const float* x     = (const float*)d_in[0];
  const float* Wf    = (const float*)d_in[1];
  const float* bf    = (const float*)d_in[2];
  const float* Wg    = (const float*)d_in[3];
  const float* bg    = (const float*)d_in[4];
  const float* Wh    = (const float*)d_in[5];
  const float* bh    = (const float*)d_in[6];
  const float* gamma = (const float*)d_in[7];
  float* out = (float*)d_out;

  char* wsb = (char*)d_ws;
  float* m2   = (float*)(wsb + 0);
  float* invD = (float*)(wsb + 131072);
  unsigned short* wA = (unsigned short*)(wsb + 262144);
  float* ball        = (float*)(wsb + 425984);
  unsigned short* fA = (unsigned short*)(wsb + 427520);
  unsigned short* gB = (unsigned short*)(wsb + 2524672);
  unsigned short* hA = (unsigned short*)(wsb + 4621824);

  k_wprep<<<40,  256, 0, stream>>>(Wf, bf, Wg, bg, Wh, bh, wA, ball);
  k_fgh  <<<512, 512, 0, stream>>>(x, wA, ball, fA, gB, hA);
  k_stats<<<256, 256, 0, stream>>>(fA, gB, m2, invD);
  k_out  <<<512, 256, 0, stream>>>(fA, gB, hA, m2, invD, x, gamma, out);
}

// Round 5
// 204.274 us; speedup vs baseline: 2.4875x; 2.4875x over previous
//
#include <hip/hip_runtime.h>
#include <hip/hip_bf16.h>

#define BB 8
#define CC 256
#define NN 4096
#define LOG2E 1.44269504088896340736f

typedef __attribute__((ext_vector_type(8))) short short8;
typedef __attribute__((ext_vector_type(4))) float f32x4;

static __device__ __forceinline__ unsigned short f2b(float x) {
  __hip_bfloat16 h = __float2bfloat16(x);   // RNE
  return *reinterpret_cast<unsigned short*>(&h);
}
static __device__ __forceinline__ unsigned int pk2(float a, float b) {
  return (unsigned int)f2b(a) | ((unsigned int)f2b(b) << 16);
}

// ---------------------------------------------------------------------------
// ws layout (bytes):
//   m2   @ 0        : [B][N] f32   row max (base-2 units)        131072
//   invD @ 131072   : [B][N] f32   1/denom                       131072
//   wA   @ 262144   : [20 mg][8 kg][64 l][8 e] bf16 W A-frags    163840
//   ball @ 425984   : [320] f32 biases (f rows pre-scaled LOG2E)   1280
//   fA   @ 427520   : [B][256 kg][64 l][8 e] bf16 (f^T*LOG2E)   2097152
//   gB   @ 2524672  : [B][256 ig][64 l][8 e] bf16               2097152
//   hA   @ 4621824  : [B][16 cg][128 kc][64 l][8 e] bf16       16777216
// Frag conventions (mfma_f32_16x16x32_bf16, m89/m91-verified):
//   A[m][k]: lane l holds m=l&15, k=(l>>4)*8+e   (B[k][n] identical bit layout)
//   D[m][n]: lane l reg r holds m=(l>>4)*4+r, n=l&15
// ---------------------------------------------------------------------------

// Kernel 0: W -> A-frags (bf16), LOG2E folded into f rows; biases -> ball.
__global__ __launch_bounds__(256) void k_wprep(
    const float* __restrict__ Wf, const float* __restrict__ bfv,
    const float* __restrict__ Wg, const float* __restrict__ bgv,
    const float* __restrict__ Wh, const float* __restrict__ bhv,
    unsigned short* __restrict__ wA, float* __restrict__ ball)
{
  const int t = threadIdx.x;
  const int fi = blockIdx.x * 4 + (t >> 6);   // frag index 0..159 (mg*8+kg)
  const int l = t & 63;
  const int mg = fi >> 3, kg = fi & 7;
  const int o = mg * 16 + (l & 15);
  const int c0 = kg * 32 + (l >> 4) * 8;
  const float* src; float scale = 1.0f;
  if (o < 32)      { src = Wf + (size_t)o * CC; scale = LOG2E; }
  else if (o < 64) { src = Wg + (size_t)(o - 32) * CC; }
  else             { src = Wh + (size_t)(o - 64) * CC; }
  float4 a = *(const float4*)(src + c0);
  float4 c = *(const float4*)(src + c0 + 4);
  short8 v;
  v[0] = (short)f2b(a.x * scale); v[1] = (short)f2b(a.y * scale);
  v[2] = (short)f2b(a.z * scale); v[3] = (short)f2b(a.w * scale);
  v[4] = (short)f2b(c.x * scale); v[5] = (short)f2b(c.y * scale);
  v[6] = (short)f2b(c.z * scale); v[7] = (short)f2b(c.w * scale);
  *(short8*)(wA + (size_t)fi * 512 + l * 8) = v;
  if (blockIdx.x == 0 && t < 320)
    ball[t] = (t < 32) ? bfv[t] * LOG2E : (t < 64) ? bgv[t - 32] : bhv[t - 64];
}

// Kernel 1: fused projection GEMM (bf16 MFMA) -> frag-ready fA/gB/hA.
__global__ __launch_bounds__(512) void k_fgh(
    const float* __restrict__ x, const unsigned short* __restrict__ wA,
    const float* __restrict__ ball,
    unsigned short* __restrict__ fA, unsigned short* __restrict__ gB,
    unsigned short* __restrict__ hA)
{
  __shared__ __align__(16) char smem[41984];       // max(xb 8KB, TL 41KB)
  unsigned short* xb = (unsigned short*)smem;      // [8 frag][64 l][8 e]
  unsigned short* TL = (unsigned short*)smem;      // [64 i][328 o] bf16
  const int bid = blockIdx.x;
  const int b = bid & 7, i0 = (bid >> 3) * 64;     // batch pinned to XCD
  const int t = threadIdx.x, w = t >> 6, l = t & 63;
  const int ig_w = w & 3, mg0 = (w >> 2) * 10;
  f32x4 acc[10] = {};
  for (int cc = 0; cc < 4; ++cc) {                 // c-chunks of 64
    __syncthreads();
    {  // stage x[cc*64..+64][i0..i0+64] as 8 B-frags (bf16)
      short8 v;
      const float* xp = x + ((size_t)b * CC + cc * 64 + w * 8) * NN + i0 + l;
      #pragma unroll
      for (int e = 0; e < 8; ++e) v[e] = (short)f2b(xp[(size_t)e * NN]);
      int frag = (w >> 2) * 4 + (l >> 4);
      int lp = (w & 3) * 16 + (l & 15);
      *(short8*)(xb + (frag * 64 + lp) * 8) = v;
    }
    __syncthreads();
    #pragma unroll
    for (int kg2 = 0; kg2 < 2; ++kg2) {
      short8 bfrag = *(const short8*)(xb + ((kg2 * 4 + ig_w) * 64 + l) * 8);
      int kg = cc * 2 + kg2;
      #pragma unroll
      for (int j = 0; j < 10; ++j) {
        short8 afrag = *(const short8*)(wA +
            ((size_t)((mg0 + j) * 8 + kg)) * 512 + l * 8);
        acc[j] = __builtin_amdgcn_mfma_f32_16x16x32_bf16(afrag, bfrag, acc[j], 0, 0, 0);
      }
    }
  }
  __syncthreads();
  // D-frags (+bias) -> transpose tile TL[i][o]
  #pragma unroll
  for (int j = 0; j < 10; ++j) {
    int ob = (mg0 + j) * 16 + (l >> 4) * 4;
    float4 bl = *(const float4*)(ball + ob);
    int irow = ig_w * 16 + (l & 15);
    ushort4 pv;
    pv.x = f2b(acc[j][0] + bl.x); pv.y = f2b(acc[j][1] + bl.y);
    pv.z = f2b(acc[j][2] + bl.z); pv.w = f2b(acc[j][3] + bl.w);
    *(ushort4*)(TL + irow * 328 + ob) = pv;
  }
  __syncthreads();
  // pack fA (o 0..31, already LOG2E-scaled) and gB (o 32..63)
  if (t < 256) {
    int kg_p = t >> 6;
    int o8 = (l >> 4) * 8;
    int irow = kg_p * 16 + (l & 15);
    short8 vf = *(const short8*)(TL + irow * 328 + o8);
    short8 vg = *(const short8*)(TL + irow * 328 + 32 + o8);
    size_t kgG = (size_t)b * 256 + (i0 >> 4) + kg_p;
    *(short8*)(fA + kgG * 512 + l * 8) = vf;
    *(short8*)(gB + kgG * 512 + l * 8) = vg;
  }
  // pack hA (o 64..319): 32 frags x 64 lanes over 512 threads
  #pragma unroll
  for (int q = 0; q < 4; ++q) {
    int slot = t + q * 512;
    int fr = slot >> 6, ll = slot & 63;
    int cg = fr >> 1, kcl = fr & 1;
    int orow = 64 + cg * 16 + (ll & 15);
    int pbase = kcl * 32 + (ll >> 4) * 8;
    short8 v;
    #pragma unroll
    for (int e = 0; e < 8; ++e) v[e] = (short)TL[(pbase + e) * 328 + orow];
    size_t idx = (((size_t)b * 16 + cg) * 128 + (i0 >> 5) + kcl) * 512 + ll * 8;
    *(short8*)(hA + idx) = v;
  }
}

// Kernel 2: single-pass online softmax stats, prefetch + barrier-lockstep
// (4 waves read the same g stream -> L1 sharing).
__global__ __launch_bounds__(256, 2) void k_stats(
    const unsigned short* __restrict__ fA, const unsigned short* __restrict__ gB,
    float* __restrict__ m2, float* __restrict__ invD)
{
  const int bid = blockIdx.x;
  const int b = bid & 7, kt = bid >> 3;            // 32 ktiles of 128 rows
  const int t = threadIdx.x, w = t >> 6, l = t & 63;
  const int li = l & 15, lh = l >> 4;
  const unsigned short* fb = fA + ((size_t)b * 256 + kt * 8 + w * 2) * 512 + l * 8;
  short8 a0 = *(const short8*)fb;
  short8 a1 = *(const short8*)(fb + 512);
  const unsigned short* gb = gB + (size_t)b * 256 * 512 + l * 8;
  f32x4 zero = {0.f, 0.f, 0.f, 0.f};
  float m[2][4], s[2][4];
  #pragma unroll
  for (int f = 0; f < 2; ++f)
    #pragma unroll
    for (int r = 0; r < 4; ++r) { m[f][r] = -1e30f; s[f][r] = 0.f; }
  short8 bcur[4], bnxt[4];
  #pragma unroll
  for (int jj = 0; jj < 4; ++jj)
    bcur[jj] = *(const short8*)(gb + (size_t)jj * 512);
  for (int j4 = 0; j4 < 64; ++j4) {
    const int jn = (j4 < 63) ? (j4 + 1) : 63;
    #pragma unroll
    for (int jj = 0; jj < 4; ++jj)
      bnxt[jj] = *(const short8*)(gb + (size_t)(jn * 4 + jj) * 512);
    f32x4 d[2][4];
    #pragma unroll
    for (int jj = 0; jj < 4; ++jj) {
      d[0][jj] = __builtin_amdgcn_mfma_f32_16x16x32_bf16(a0, bcur[jj], zero, 0, 0, 0);
      d[1][jj] = __builtin_amdgcn_mfma_f32_16x16x32_bf16(a1, bcur[jj], zero, 0, 0, 0);
    }
    #pragma unroll
    for (int f = 0; f < 2; ++f)
      #pragma unroll
      for (int r = 0; r < 4; ++r) {
        float cm = fmaxf(fmaxf(d[f][0][r], d[f][1][r]),
                         fmaxf(d[f][2][r], d[f][3][r]));
        float mn = fmaxf(m[f][r], cm);
        float a = (exp2f(d[f][0][r] - mn) + exp2f(d[f][1][r] - mn))
                + (exp2f(d[f][2][r] - mn) + exp2f(d[f][3][r] - mn));
        s[f][r] = s[f][r] * exp2f(m[f][r] - mn) + a;
        m[f][r] = mn;
      }
    #pragma unroll
    for (int jj = 0; jj < 4; ++jj) bcur[jj] = bnxt[jj];
    __syncthreads();   // keep waves lockstep: shared g stream stays L1-hot
  }
  #pragma unroll
  for (int mk = 1; mk < 16; mk <<= 1)
    #pragma unroll
    for (int f = 0; f < 2; ++f)
      #pragma unroll
      for (int r = 0; r < 4; ++r) {
        float om = __shfl_xor(m[f][r], mk);
        float os = __shfl_xor(s[f][r], mk);
        float mn = fmaxf(m[f][r], om);
        s[f][r] = s[f][r] * exp2f(m[f][r] - mn) + os * exp2f(om - mn);
        m[f][r] = mn;
      }
  if (li == 0) {
    #pragma unroll
    for (int f = 0; f < 2; ++f)
      #pragma unroll
      for (int r = 0; r < 4; ++r) {
        size_t idx = (size_t)b * NN + kt * 128 + w * 32 + f * 16 + lh * 4 + r;
        m2[idx] = m[f][r];
        invD[idx] = 1.0f / s[f][r];
      }
  }
}

// Kernel 3: out[c][i] via D[i][c] = P^T . h^T (same operand bytes as h.P).
// 4 waves; wave w: c-strip [w*64, w*64+64), i-tile 64, K-chunks of 64.
// S D-frag -> P B-frag via ONE ds_write_b64 (direct scatter), dbuf LDS,
// one barrier/chunk, depth-1 prefetch of all global operands.
__global__ __launch_bounds__(256, 2) void k_out(
    const unsigned short* __restrict__ fA, const unsigned short* __restrict__ gB,
    const unsigned short* __restrict__ hA,
    const float* __restrict__ m2v, const float* __restrict__ invDv,
    const float* __restrict__ x, const float* __restrict__ gamma,
    float* __restrict__ out)
{
  __shared__ __align__(16) unsigned short pbuf[2 * 8 * 512];   // 2 x 8 KB
  const int bid = blockIdx.x;
  const int b = bid & 7, i0 = (bid >> 3) * 64;     // batch pinned to XCD
  const int t = threadIdx.x, w = t >> 6, l = t & 63;
  const int li = l & 15, lh = l >> 4;
  const unsigned short* fAb = fA + (size_t)b * 256 * 512 + l * 8;
  const unsigned short* hAb = hA + ((size_t)b * 16 + w * 4) * (size_t)128 * 512 + l * 8;
  const float* m2 = m2v + (size_t)b * NN + w * 16 + lh * 4;
  const float* invD = invDv + (size_t)b * NN + w * 16 + lh * 4;
  // persistent g B-frags for the 4 ig of this block's i-tile
  short8 g[4];
  #pragma unroll
  for (int ig = 0; ig < 4; ++ig)
    g[ig] = *(const short8*)(gB + ((size_t)b * 256 + (i0 >> 4) + ig) * 512 + l * 8);
  // scatter slot: S-frag (kg=w) -> P B-frag (kb2=w>>1), lane pl, words j0,j0+1
  const int pl = ((w & 1) * 2 + (lh >> 1)) * 16 + li;
  const int j0 = (lh & 1) * 2;
  // prefetch chunk 0
  short8 fcur = *(const short8*)(fAb + (size_t)w * 512);
  short8 hcur[8];
  #pragma unroll
  for (int cg = 0; cg < 4; ++cg) {
    hcur[cg * 2]     = *(const short8*)(hAb + (size_t)cg * 128 * 512);
    hcur[cg * 2 + 1] = *(const short8*)(hAb + ((size_t)cg * 128 + 1) * 512);
  }
  float4 mmcur = *(const float4*)(m2);
  float4 ddcur = *(const float4*)(invD);
  f32x4 zero = {0.f, 0.f, 0.f, 0.f};
  f32x4 acc[4][4] = {};
  for (int ch = 0; ch < 64; ++ch) {
    // ---- S phase: 4 MFMAs (kg=w, ig 0..3) using prefetched fcur
    f32x4 sfr[4];
    #pragma unroll
    for (int ig = 0; ig < 4; ++ig)
      sfr[ig] = __builtin_amdgcn_mfma_f32_16x16x32_bf16(fcur, g[ig], zero, 0, 0, 0);
    // ---- issue next chunk's global loads (consumed next iteration)
    const int chn = (ch < 63) ? (ch + 1) : 63;
    short8 fnxt = *(const short8*)(fAb + (size_t)(chn * 4 + w) * 512);
    short8 hnxt[8];
    #pragma unroll
    for (int cg = 0; cg < 4; ++cg) {
      hnxt[cg * 2]     = *(const short8*)(hAb + ((size_t)cg * 128 + chn * 2) * 512);
      hnxt[cg * 2 + 1] = *(const short8*)(hAb + ((size_t)cg * 128 + chn * 2 + 1) * 512);
    }
    float4 mmn = *(const float4*)(m2 + chn * 64);
    float4 ddn = *(const float4*)(invD + chn * 64);
    // ---- exp2 + pack + direct scatter into P B-frag image
    unsigned short* pb = pbuf + (ch & 1) * (8 * 512);
    #pragma unroll
    for (int ig = 0; ig < 4; ++ig) {
      float p0 = exp2f(sfr[ig][0] - mmcur.x) * ddcur.x;
      float p1 = exp2f(sfr[ig][1] - mmcur.y) * ddcur.y;
      float p2 = exp2f(sfr[ig][2] - mmcur.z) * ddcur.z;
      float p3 = exp2f(sfr[ig][3] - mmcur.w) * ddcur.w;
      uint2 v; v.x = pk2(p0, p1); v.y = pk2(p2, p3);
      unsigned short* fragp = pb + ((w >> 1) * 4 + ig) * 512;
      *(uint2*)(fragp + pl * 8 + j0 * 2) = v;
    }
    __syncthreads();
    // ---- PV phase: 32 MFMAs; P frags from LDS, h from prefetched regs
    #pragma unroll
    for (int kb2 = 0; kb2 < 2; ++kb2)
      #pragma unroll
      for (int ig = 0; ig < 4; ++ig) {
        short8 pf = *(const short8*)(pb + ((kb2 * 4 + ig) * 64 + l) * 8);
        #pragma unroll
        for (int cg = 0; cg < 4; ++cg)
          acc[cg][ig] = __builtin_amdgcn_mfma_f32_16x16x32_bf16(
              pf, hcur[cg * 2 + kb2], acc[cg][ig], 0, 0, 0);
      }
    // ---- rotate prefetch
    fcur = fnxt; mmcur = mmn; ddcur = ddn;
    #pragma unroll
    for (int q = 0; q < 8; ++q) hcur[q] = hnxt[q];
  }
  // epilogue: D[m=i][n=c] -> lane holds 4 consecutive i at fixed c
  const float gm = gamma[0];
  #pragma unroll
  for (int cg = 0; cg < 4; ++cg)
    #pragma unroll
    for (int ig = 0; ig < 4; ++ig) {
      int c = w * 64 + cg * 16 + li;
      int i = i0 + ig * 16 + lh * 4;
      size_t off = ((size_t)b * CC + c) * NN + i;
      float4 xv = *(const float4*)(x + off);
      float4 ov;
      ov.x = gm * acc[cg][ig][0] + xv.x;
      ov.y = gm * acc[cg][ig][1] + xv.y;
      ov.z = gm * acc[cg][ig][2] + xv.z;
      ov.w = gm * acc[cg][ig][3] + xv.w;
      *(float4*)(out + off) = ov;
    }
}

extern "C" void kernel_launch(void* const* d_in, const int* in_sizes, int n_in,
                              void* d_out, int out_size, void* d_ws, size_t ws_size,
                              hipStream_t stream)
{
  const float* x     = (const float*)d_in[0];
  const float* Wf    = (const float*)d_in[1];
  const float* bf    = (const float*)d_in[2];
  const float* Wg    = (const float*)d_in[3];
  const float* bg    = (const float*)d_in[4];
  const float* Wh    = (const float*)d_in[5];
  const float* bh    = (const float*)d_in[6];
  const float* gamma = (const float*)d_in[7];
  float* out = (float*)d_out;

  char* wsb = (char*)d_ws;
  float* m2   = (float*)(wsb + 0);
  float* invD = (float*)(wsb + 131072);
  unsigned short* wA = (unsigned short*)(wsb + 262144);
  float* ball        = (float*)(wsb + 425984);
  unsigned short* fA = (unsigned short*)(wsb + 427520);
  unsigned short* gB = (unsigned short*)(wsb + 2524672);
  unsigned short* hA = (unsigned short*)(wsb + 4621824);

  k_wprep<<<40,  256, 0, stream>>>(Wf, bf, Wg, bg, Wh, bh, wA, ball);
  k_fgh  <<<512, 512, 0, stream>>>(x, wA, ball, fA, gB, hA);
  k_stats<<<256, 256, 0, stream>>>(fA, gB, m2, invD);
  k_out  <<<512, 256, 0, stream>>>(fA, gB, hA, m2, invD, x, gamma, out);
}

// Round 6
// 159.970 us; speedup vs baseline: 3.1765x; 1.2770x over previous
//
#include <hip/hip_runtime.h>
#include <hip/hip_bf16.h>

#define BB 8
#define CC 256
#define NN 4096
#define LOG2E 1.44269504088896340736f
#define SHIFT 48.0f

typedef __attribute__((ext_vector_type(8))) short short8;
typedef __attribute__((ext_vector_type(4))) float f32x4;

static __device__ __forceinline__ unsigned short f2b(float x) {
  __hip_bfloat16 h = __float2bfloat16(x);   // RNE
  return *reinterpret_cast<unsigned short*>(&h);
}
static __device__ __forceinline__ unsigned int pk2(float a, float b) {
  return (unsigned int)f2b(a) | ((unsigned int)f2b(b) << 16);
}

// ---------------------------------------------------------------------------
// ws layout (bytes):
//   (unused)@ 0     : 131072 (was m2 — removed, fixed-shift softmax)
//   cshift @ 131072 : [B][N] f32  c[k] = SHIFT + log2(sum exp2(S-SHIFT))
//   wA   @ 262144   : [20 mg][8 kg][64 l][8 e] bf16 W A-frags    163840
//   ball @ 425984   : [320] f32 biases (f rows pre-scaled LOG2E)   1280
//   fA   @ 427520   : [B][256 kg][64 l][8 e] bf16 (f^T*LOG2E)   2097152
//   gB   @ 2524672  : [B][256 ig][64 l][8 e] bf16               2097152
//   hA   @ 4621824  : [B][16 cg][128 kc][64 l][8 e] bf16       16777216
// Frag conventions (mfma_f32_16x16x32_bf16, m89/m91-verified):
//   A[m][k]: lane l holds m=l&15, k=(l>>4)*8+e   (B[k][n] identical bit layout)
//   D[m][n]: lane l reg r holds m=(l>>4)*4+r, n=l&15
// P = exp2(S - c[k]) with c >= rowmax  ->  P in [0,1], no inf/NaN possible.
// ---------------------------------------------------------------------------

// Kernel 0: W -> A-frags (bf16), LOG2E folded into f rows; biases -> ball.
__global__ __launch_bounds__(256) void k_wprep(
    const float* __restrict__ Wf, const float* __restrict__ bfv,
    const float* __restrict__ Wg, const float* __restrict__ bgv,
    const float* __restrict__ Wh, const float* __restrict__ bhv,
    unsigned short* __restrict__ wA, float* __restrict__ ball)
{
  const int t = threadIdx.x;
  const int fi = blockIdx.x * 4 + (t >> 6);   // frag index 0..159 (mg*8+kg)
  const int l = t & 63;
  const int mg = fi >> 3, kg = fi & 7;
  const int o = mg * 16 + (l & 15);
  const int c0 = kg * 32 + (l >> 4) * 8;
  const float* src; float scale = 1.0f;
  if (o < 32)      { src = Wf + (size_t)o * CC; scale = LOG2E; }
  else if (o < 64) { src = Wg + (size_t)(o - 32) * CC; }
  else             { src = Wh + (size_t)(o - 64) * CC; }
  float4 a = *(const float4*)(src + c0);
  float4 c = *(const float4*)(src + c0 + 4);
  short8 v;
  v[0] = (short)f2b(a.x * scale); v[1] = (short)f2b(a.y * scale);
  v[2] = (short)f2b(a.z * scale); v[3] = (short)f2b(a.w * scale);
  v[4] = (short)f2b(c.x * scale); v[5] = (short)f2b(c.y * scale);
  v[6] = (short)f2b(c.z * scale); v[7] = (short)f2b(c.w * scale);
  *(short8*)(wA + (size_t)fi * 512 + l * 8) = v;
  if (blockIdx.x == 0 && t < 320)
    ball[t] = (t < 32) ? bfv[t] * LOG2E : (t < 64) ? bgv[t - 32] : bhv[t - 64];
}

// Kernel 1: fused projection GEMM (bf16 MFMA) -> frag-ready fA/gB/hA.
__global__ __launch_bounds__(512) void k_fgh(
    const float* __restrict__ x, const unsigned short* __restrict__ wA,
    const float* __restrict__ ball,
    unsigned short* __restrict__ fA, unsigned short* __restrict__ gB,
    unsigned short* __restrict__ hA)
{
  __shared__ __align__(16) char smem[41984];       // max(xb 8KB, TL 41KB)
  unsigned short* xb = (unsigned short*)smem;      // [8 frag][64 l][8 e]
  unsigned short* TL = (unsigned short*)smem;      // [64 i][328 o] bf16
  const int bid = blockIdx.x;
  const int b = bid & 7, i0 = (bid >> 3) * 64;     // batch pinned to XCD
  const int t = threadIdx.x, w = t >> 6, l = t & 63;
  const int ig_w = w & 3, mg0 = (w >> 2) * 10;
  f32x4 acc[10] = {};
  for (int cc = 0; cc < 4; ++cc) {                 // c-chunks of 64
    __syncthreads();
    {  // stage x[cc*64..+64][i0..i0+64] as 8 B-frags (bf16)
      short8 v;
      const float* xp = x + ((size_t)b * CC + cc * 64 + w * 8) * NN + i0 + l;
      #pragma unroll
      for (int e = 0; e < 8; ++e) v[e] = (short)f2b(xp[(size_t)e * NN]);
      int frag = (w >> 2) * 4 + (l >> 4);
      int lp = (w & 3) * 16 + (l & 15);
      *(short8*)(xb + (frag * 64 + lp) * 8) = v;
    }
    __syncthreads();
    #pragma unroll
    for (int kg2 = 0; kg2 < 2; ++kg2) {
      short8 bfrag = *(const short8*)(xb + ((kg2 * 4 + ig_w) * 64 + l) * 8);
      int kg = cc * 2 + kg2;
      #pragma unroll
      for (int j = 0; j < 10; ++j) {
        short8 afrag = *(const short8*)(wA +
            ((size_t)((mg0 + j) * 8 + kg)) * 512 + l * 8);
        acc[j] = __builtin_amdgcn_mfma_f32_16x16x32_bf16(afrag, bfrag, acc[j], 0, 0, 0);
      }
    }
  }
  __syncthreads();
  // D-frags (+bias) -> transpose tile TL[i][o]
  #pragma unroll
  for (int j = 0; j < 10; ++j) {
    int ob = (mg0 + j) * 16 + (l >> 4) * 4;
    float4 bl = *(const float4*)(ball + ob);
    int irow = ig_w * 16 + (l & 15);
    ushort4 pv;
    pv.x = f2b(acc[j][0] + bl.x); pv.y = f2b(acc[j][1] + bl.y);
    pv.z = f2b(acc[j][2] + bl.z); pv.w = f2b(acc[j][3] + bl.w);
    *(ushort4*)(TL + irow * 328 + ob) = pv;
  }
  __syncthreads();
  // pack fA (o 0..31, already LOG2E-scaled) and gB (o 32..63)
  if (t < 256) {
    int kg_p = t >> 6;
    int o8 = (l >> 4) * 8;
    int irow = kg_p * 16 + (l & 15);
    short8 vf = *(const short8*)(TL + irow * 328 + o8);
    short8 vg = *(const short8*)(TL + irow * 328 + 32 + o8);
    size_t kgG = (size_t)b * 256 + (i0 >> 4) + kg_p;
    *(short8*)(fA + kgG * 512 + l * 8) = vf;
    *(short8*)(gB + kgG * 512 + l * 8) = vg;
  }
  // pack hA (o 64..319): 32 frags x 64 lanes over 512 threads
  #pragma unroll
  for (int q = 0; q < 4; ++q) {
    int slot = t + q * 512;
    int fr = slot >> 6, ll = slot & 63;
    int cg = fr >> 1, kcl = fr & 1;
    int orow = 64 + cg * 16 + (ll & 15);
    int pbase = kcl * 32 + (ll >> 4) * 8;
    short8 v;
    #pragma unroll
    for (int e = 0; e < 8; ++e) v[e] = (short)TL[(pbase + e) * 328 + orow];
    size_t idx = (((size_t)b * 16 + cg) * 128 + (i0 >> 5) + kcl) * 512 + ll * 8;
    *(short8*)(hA + idx) = v;
  }
}

// Kernel 2: fixed-shift softmax denom. cshift[k] = SHIFT + log2(sum exp2(S-SHIFT)).
// 4 waves x 16 k-rows; g B-frags streamed from L1/L2, depth-1 prefetch,
// no max tracking, no barriers.
__global__ __launch_bounds__(256, 4) void k_stats(
    const unsigned short* __restrict__ fA, const unsigned short* __restrict__ gB,
    float* __restrict__ cshift)
{
  const int bid = blockIdx.x;
  const int b = bid & 7, kt = bid >> 3;            // 64 ktiles of 64 rows
  const int t = threadIdx.x, w = t >> 6, l = t & 63;
  const int li = l & 15, lh = l >> 4;
  short8 af = *(const short8*)(fA + ((size_t)b * 256 + kt * 4 + w) * 512 + l * 8);
  const unsigned short* gb = gB + (size_t)b * 256 * 512 + l * 8;
  f32x4 zero = {0.f, 0.f, 0.f, 0.f};
  float s[4] = {0.f, 0.f, 0.f, 0.f};
  short8 bc[4], bn[4];
  #pragma unroll
  for (int jj = 0; jj < 4; ++jj)
    bc[jj] = *(const short8*)(gb + (size_t)jj * 512);
  for (int j4 = 0; j4 < 64; ++j4) {
    const int jn = (j4 < 63) ? (j4 + 1) : 63;
    #pragma unroll
    for (int jj = 0; jj < 4; ++jj)
      bn[jj] = *(const short8*)(gb + (size_t)(jn * 4 + jj) * 512);
    #pragma unroll
    for (int jj = 0; jj < 4; ++jj) {
      f32x4 d = __builtin_amdgcn_mfma_f32_16x16x32_bf16(af, bc[jj], zero, 0, 0, 0);
      s[0] += exp2f(d[0] - SHIFT);
      s[1] += exp2f(d[1] - SHIFT);
      s[2] += exp2f(d[2] - SHIFT);
      s[3] += exp2f(d[3] - SHIFT);
    }
    #pragma unroll
    for (int jj = 0; jj < 4; ++jj) bc[jj] = bn[jj];
  }
  // reduce over the 16 j-columns (lane bits 0..3)
  #pragma unroll
  for (int mk = 1; mk < 16; mk <<= 1)
    #pragma unroll
    for (int r = 0; r < 4; ++r) s[r] += __shfl_xor(s[r], mk);
  if (li == 0) {
    #pragma unroll
    for (int r = 0; r < 4; ++r) {
      size_t idx = (size_t)b * NN + kt * 64 + w * 16 + lh * 4 + r;
      cshift[idx] = SHIFT + log2f(fmaxf(s[r], 1e-30f));
    }
  }
}

// Kernel 3: out[c][i] via D[i][c] = P^T . h^T. 8 waves, chunk = 128 k.
// Wave w: S for kg = ch*8+w (4 ig) -> scatter one uint2/ig into P B-frag
// image; PV: c-strip w*32..+32, 32 MFMA from LDS P + L2-streamed h.
// One barrier per chunk, dbuf 2x16KB LDS, 4 waves/SIMD for TLP.
__global__ __launch_bounds__(512, 4) void k_out(
    const unsigned short* __restrict__ fA, const unsigned short* __restrict__ gB,
    const unsigned short* __restrict__ hA,
    const float* __restrict__ csv,
    const float* __restrict__ x, const float* __restrict__ gamma,
    float* __restrict__ out)
{
  __shared__ __align__(16) unsigned short pbuf[2 * 16 * 512];   // 2 x 16 KB
  const int bid = blockIdx.x;
  const int b = bid & 7, i0 = (bid >> 3) * 64;     // batch pinned to XCD
  const int t = threadIdx.x, w = t >> 6, l = t & 63;
  const int li = l & 15, lh = l >> 4;
  const unsigned short* fAb = fA + ((size_t)b * 256 + w) * 512 + l * 8;
  const unsigned short* hAb = hA + ((size_t)b * 16 + w * 2) * (size_t)128 * 512 + l * 8;
  const float* cs = csv + (size_t)b * NN + w * 16 + lh * 4;
  // persistent g B-frags for this block's 4 ig columns
  short8 g[4];
  #pragma unroll
  for (int ig = 0; ig < 4; ++ig)
    g[ig] = *(const short8*)(gB + ((size_t)b * 256 + (i0 >> 4) + ig) * 512 + l * 8);
  // scatter slot: wave's S rows (k_loc32 = (w&1)*16+lh*4+r) -> B-frag lane/elems
  const int pl = ((w & 1) * 2 + (lh >> 1)) * 16 + li;   // target lane
  const int pwo = pl * 8 + (lh & 1) * 4;                // ushort offset in frag
  f32x4 zero = {0.f, 0.f, 0.f, 0.f};
  f32x4 acc[2][4] = {};
  for (int ch = 0; ch < 32; ++ch) {
    // issue h B-frag loads early (consumed after the barrier)
    short8 hf[8];
    #pragma unroll
    for (int cg = 0; cg < 2; ++cg)
      #pragma unroll
      for (int kb = 0; kb < 4; ++kb)
        hf[cg * 4 + kb] = *(const short8*)(hAb +
            ((size_t)cg * 128 + ch * 4 + kb) * 512);
    // S phase: kg = ch*8 + w
    short8 af = *(const short8*)(fAb + (size_t)ch * 8 * 512);
    float4 cc = *(const float4*)(cs + ch * 128);
    unsigned short* pb = pbuf + (ch & 1) * (16 * 512);
    #pragma unroll
    for (int ig = 0; ig < 4; ++ig) {
      f32x4 sfr = __builtin_amdgcn_mfma_f32_16x16x32_bf16(af, g[ig], zero, 0, 0, 0);
      uint2 v;
      v.x = pk2(exp2f(sfr[0] - cc.x), exp2f(sfr[1] - cc.y));
      v.y = pk2(exp2f(sfr[2] - cc.z), exp2f(sfr[3] - cc.w));
      *(uint2*)(pb + ((size_t)((w >> 1) * 4 + ig)) * 512 + pwo) = v;
    }
    __syncthreads();
    // PV phase: 32 MFMA; P frags from LDS, h from regs
    #pragma unroll
    for (int kb = 0; kb < 4; ++kb)
      #pragma unroll
      for (int ig = 0; ig < 4; ++ig) {
        short8 pf = *(const short8*)(pb + ((kb * 4 + ig) * 64 + l) * 8);
        acc[0][ig] = __builtin_amdgcn_mfma_f32_16x16x32_bf16(pf, hf[kb], acc[0][ig], 0, 0, 0);
        acc[1][ig] = __builtin_amdgcn_mfma_f32_16x16x32_bf16(pf, hf[4 + kb], acc[1][ig], 0, 0, 0);
      }
  }
  // epilogue: D[m=i][n=c] -> lane holds 4 consecutive i at fixed c
  const float gm = gamma[0];
  #pragma unroll
  for (int cg = 0; cg < 2; ++cg)
    #pragma unroll
    for (int ig = 0; ig < 4; ++ig) {
      int c = w * 32 + cg * 16 + li;
      int i = i0 + ig * 16 + lh * 4;
      size_t off = ((size_t)b * CC + c) * NN + i;
      float4 xv = *(const float4*)(x + off);
      float4 ov;
      ov.x = gm * acc[cg][ig][0] + xv.x;
      ov.y = gm * acc[cg][ig][1] + xv.y;
      ov.z = gm * acc[cg][ig][2] + xv.z;
      ov.w = gm * acc[cg][ig][3] + xv.w;
      *(float4*)(out + off) = ov;
    }
}

extern "C" void kernel_launch(void* const* d_in, const int* in_sizes, int n_in,
                              void* d_out, int out_size, void* d_ws, size_t ws_size,
                              hipStream_t stream)
{
  const float* x     = (const float*)d_in[0];
  const float* Wf    = (const float*)d_in[1];
  const float* bf    = (const float*)d_in[2];
  const float* Wg    = (const float*)d_in[3];
  const float* bg    = (const float*)d_in[4];
  const float* Wh    = (const float*)d_in[5];
  const float* bh    = (const float*)d_in[6];
  const float* gamma = (const float*)d_in[7];
  float* out = (float*)d_out;

  char* wsb = (char*)d_ws;
  float* cshift = (float*)(wsb + 131072);
  unsigned short* wA = (unsigned short*)(wsb + 262144);
  float* ball        = (float*)(wsb + 425984);
  unsigned short* fA = (unsigned short*)(wsb + 427520);
  unsigned short* gB = (unsigned short*)(wsb + 2524672);
  unsigned short* hA = (unsigned short*)(wsb + 4621824);

  k_wprep<<<40,  256, 0, stream>>>(Wf, bf, Wg, bg, Wh, bh, wA, ball);
  k_fgh  <<<512, 512, 0, stream>>>(x, wA, ball, fA, gB, hA);
  k_stats<<<512, 256, 0, stream>>>(fA, gB, cshift);
  k_out  <<<512, 512, 0, stream>>>(fA, gB, hA, cshift, x, gamma, out);
}